// Round 2
// baseline (2485.651 us; speedup 1.0000x reference)
//
#include <hip/hip_runtime.h>

#define BB 4
#define TT 32
#define DD 256
#define NN 1024

// ws layout (float indices)
#define XN_OFF   0                      // xn [B*T][N]
#define TN_OFF   131072                 // tn [B*T][N]  (tn[b][t] = tgt_neurons[b][t+1])
#define PB_OFF   262144                 // p  [B*T][2][N]
#define RB_OFF   524288                 // r  [B*T][N]
#define FLG_OFF  655360                 // wave flags [3 stages][4 b][16 wg][8 waves], stride 8 u32 (32B)
#define FLG_WORDS 12288                 // 3*4*16*8 * 8
#define WS_END   (FLG_OFF + FLG_WORDS)  // 667648 — identical footprint to the original kernel

// ---------------- kernel 1: xn = relu(LN(x @ E)), tn shifted; grid = 64 ----------------
__global__ __launch_bounds__(256) void precompute_kernel(
    const float* __restrict__ x_seq, const float* __restrict__ targets,
    const float* __restrict__ E, float* __restrict__ ws)
{
    __shared__ float xr[4][DD];
    __shared__ float redS[4][4], redSS[4][4];
    const int blk = blockIdx.x;        // 0..63
    const int bt0 = blk * 2, bt1 = bt0 + 1;
    const int tid = threadIdx.x;
    const int lane = tid & 63, w = tid >> 6;

    xr[0][tid] = x_seq[(size_t)bt0 * DD + tid];
    xr[1][tid] = x_seq[(size_t)bt1 * DD + tid];
    xr[2][tid] = targets[(size_t)bt0 * DD + tid];
    xr[3][tid] = targets[(size_t)bt1 * DD + tid];
    __syncthreads();

    const float4* E4 = (const float4*)E;
    float4 acc[4];
#pragma unroll
    for (int r = 0; r < 4; ++r) acc[r] = make_float4(0.f, 0.f, 0.f, 0.f);
#pragma unroll 4
    for (int k = 0; k < DD; ++k) {
        float4 e = E4[(size_t)k * (NN / 4) + tid];
#pragma unroll
        for (int r = 0; r < 4; ++r) {
            float xv = xr[r][k];
            acc[r].x += xv * e.x; acc[r].y += xv * e.y;
            acc[r].z += xv * e.z; acc[r].w += xv * e.w;
        }
    }
    float s[4], ss[4];
#pragma unroll
    for (int r = 0; r < 4; ++r) {
        s[r]  = acc[r].x + acc[r].y + acc[r].z + acc[r].w;
        ss[r] = acc[r].x*acc[r].x + acc[r].y*acc[r].y + acc[r].z*acc[r].z + acc[r].w*acc[r].w;
    }
#pragma unroll
    for (int d = 1; d < 64; d <<= 1) {
#pragma unroll
        for (int r = 0; r < 4; ++r) {
            s[r]  += __shfl_xor(s[r], d, 64);
            ss[r] += __shfl_xor(ss[r], d, 64);
        }
    }
    if (lane == 0) {
#pragma unroll
        for (int r = 0; r < 4; ++r) { redS[w][r] = s[r]; redSS[w][r] = ss[r]; }
    }
    __syncthreads();
#pragma unroll
    for (int r = 0; r < 4; ++r) {
        s[r]  = redS[0][r] + redS[1][r] + redS[2][r] + redS[3][r];
        ss[r] = redSS[0][r] + redSS[1][r] + redSS[2][r] + redSS[3][r];
    }
#pragma unroll
    for (int r = 0; r < 4; ++r) {
        const float mu  = s[r] * (1.0f / NN);
        const float var = ss[r] * (1.0f / NN) - mu * mu;
        const float inv = rsqrtf(var + 1e-5f);
        float4 o;
        o.x = fmaxf(0.f, (acc[r].x - mu) * inv);
        o.y = fmaxf(0.f, (acc[r].y - mu) * inv);
        o.z = fmaxf(0.f, (acc[r].z - mu) * inv);
        o.w = fmaxf(0.f, (acc[r].w - mu) * inv);
        const int bt = (r & 1) ? bt1 : bt0;
        float* dst = nullptr;
        if (r < 2) dst = ws + XN_OFF + (size_t)bt * NN;
        else if ((bt & 31) > 0) dst = ws + TN_OFF + (size_t)(bt - 1) * NN;
        if (dst) ((float4*)dst)[tid] = o;
    }
}

// ---------------- kernel 2: barrier-free per-wave pipeline ----------------
__device__ __forceinline__ float ald(const float* p) {
    return __hip_atomic_load(p, __ATOMIC_RELAXED, __HIP_MEMORY_SCOPE_AGENT);
}
__device__ __forceinline__ void ast(float* p, float v) {
    __hip_atomic_store(p, v, __ATOMIC_RELAXED, __HIP_MEMORY_SCOPE_AGENT);
}
__device__ __forceinline__ unsigned aldu_acq(const unsigned* p) {
    return __hip_atomic_load(p, __ATOMIC_ACQUIRE, __HIP_MEMORY_SCOPE_AGENT);
}

__global__ __launch_bounds__(512, 1) void mega_kernel(
    const float* __restrict__ Dy, float* __restrict__ out, float* __restrict__ ws)
{
    __shared__ float sh[6144];   // used only by the out stage
    const int blk = blockIdx.x;  // 0..223
    const int tid = threadIdx.x;

    // XCD-locality remap: dispatch round-robins blockIdx across the 8 XCDs (blk % 8).
    const int xcd  = blk & 7;
    const int slot = blk >> 3;               // 0..27
    const int b    = xcd >> 1;               // 0..3
    const int idx  = (xcd & 1) * 28 + slot;  // 0..55 role index within batch

    float* pb     = ws + PB_OFF;
    float* rb     = ws + RB_OFF;
    unsigned* flg = (unsigned*)(ws + FLG_OFF);

    if (idx < 48) {
        // ---- chain stages 0,1,2 : fully barrier-free, per-wave autonomy ----
        const int stage = idx >> 4;          // 0,1,2
        const int wg    = idx & 15;
        const int lane  = tid & 63;
        const int w     = tid >> 6;
        const int colbase = wg * 64 + w * 8;   // wave owns output cols colbase..+7
        const float* xn = ws + XN_OFF + (size_t)b * TT * NN;
        const float* tn = ws + TN_OFF + (size_t)b * TT * NN;

        // per-(wg,wave) flag, monotone step counter, own 32B line
        unsigned* myflag = flg + ((size_t)((stage * 4 + b) * 16 + wg) * 8 + w) * 8;
        // producer wave flags of the previous stage (128 of them)
        const unsigned* pflags = flg + (size_t)((stage - 1) * 4 + b) * 16 * 8 * 8;
        // lane l polls producer (wg = l&15, waves (l>>4)*2 and +1): covers all 128 per wave
        const unsigned* f0 = pflags + ((size_t)((lane & 15) * 8 + (lane >> 4) * 2)) * 8;
        const unsigned* f1 = f0 + 8;

        // G slice: lane holds rows {i*64 + lane}, cols colbase..+7 (interleaved rows
        // => all gather/x loads are 256B-contiguous per wave)
        float G[16][8];
#pragma unroll
        for (int i = 0; i < 16; ++i)
#pragma unroll
            for (int c = 0; c < 8; ++c)
                G[i][c] = (i * 64 + lane == colbase + c) ? 0.01f : 0.0f;

        float x[16], tv[8];
        unsigned seen = 0;

#pragma unroll 1
        for (int t = 0; t < TT; ++t) {
            const int bt = b * TT + t;
            float* p1 = pb + (size_t)bt * 2 * NN;
            float* p2 = p1 + NN;

            float in[16];
            float v1own = 0.f, v2own = 0.f;

            if (stage == 0) {
#pragma unroll
                for (int i = 0; i < 16; ++i) {
                    x[i] = xn[(size_t)t * NN + i * 64 + lane];
                    in[i] = x[i];
                }
            } else {
                // wave-level wait: all 128 producer waves at step >= t+1 (seen is monotone)
                const unsigned tgt = (unsigned)(t + 1);
                if (!__all(seen >= tgt)) {
                    int g = 0;
                    for (;;) {
                        unsigned v0 = aldu_acq(f0), v1 = aldu_acq(f1);
                        unsigned m = v0 < v1 ? v0 : v1;
                        if (m > seen) seen = m;
                        if (__all(seen >= tgt)) break;
                        __builtin_amdgcn_s_sleep(1);
                        if (++g > (1 << 22)) break;  // fail visibly, never hang
                    }
                }
                // direct coalesced gather of the full input vector fragment
                const float* src = (stage == 1) ? p1 : p2;
#pragma unroll
                for (int i = 0; i < 16; ++i) in[i] = ald(src + i * 64 + lane);
                if (stage == 2) {
                    v1own = ald(p1 + colbase + (lane & 7));
                    v2own = ald(p2 + colbase + (lane & 7));
                }
                // deferred G-update for step t-1: VALU hides under the gather latency
                if (t > 0) {
#pragma unroll
                    for (int c = 0; c < 8; ++c)
#pragma unroll
                        for (int i = 0; i < 16; ++i)
                            G[i][c] = fmaxf(G[i][c], x[i] * tv[c]);
                }
            }

            // matvec: acc[c] = partial sum for col colbase+c over this lane's rows
            float acc[8] = {0.f,0.f,0.f,0.f,0.f,0.f,0.f,0.f};
#pragma unroll
            for (int i = 0; i < 16; ++i)
#pragma unroll
                for (int c = 0; c < 8; ++c) acc[c] += in[i] * G[i][c];

            // reduce-scatter: lane ends with full sum for col colbase + (lane&7)
            float t4[8];
#pragma unroll
            for (int c = 0; c < 8; ++c) t4[c] = __shfl_xor(acc[c], 4, 64);
            const bool k2 = (lane & 4) != 0;
            float s4[4];
#pragma unroll
            for (int k = 0; k < 4; ++k) s4[k] = k2 ? (acc[4+k] + t4[4+k]) : (acc[k] + t4[k]);
            float t2[4];
#pragma unroll
            for (int k = 0; k < 4; ++k) t2[k] = __shfl_xor(s4[k], 2, 64);
            const bool k1 = (lane & 2) != 0;
            float s2[2];
#pragma unroll
            for (int k = 0; k < 2; ++k) s2[k] = k1 ? (s4[2+k] + t2[2+k]) : (s4[k] + t2[k]);
            float t1[2];
#pragma unroll
            for (int k = 0; k < 2; ++k) t1[k] = __shfl_xor(s2[k], 1, 64);
            float v = (lane & 1) ? (s2[1] + t1[1]) : (s2[0] + t1[0]);
            v += __shfl_xor(v, 8, 64);
            v += __shfl_xor(v, 16, 64);
            v += __shfl_xor(v, 32, 64);

            // wave-local store + wave flag release (release's vmcnt(0) covers the stores)
            if (stage == 0) {
                if (lane < 8) ast(p1 + colbase + lane, v);
            } else if (stage == 1) {
                if (lane < 8) ast(p2 + colbase + lane, v);
            } else {
                float r = fmaxf(v, fmaxf(v1own, v2own));
                if (lane < 8) ast(rb + (size_t)bt * NN + colbase + lane, r);
            }
            if (lane == 0)
                __hip_atomic_store(myflag, (unsigned)(t + 1),
                                   __ATOMIC_RELEASE, __HIP_MEMORY_SCOPE_AGENT);

            // prefetch x/tv of step t (stage!=0: consumed by next iter's deferred update;
            // stage 0: update immediately — its x is already this step's input)
            if (t < TT - 1) {
                if (stage != 0) {
#pragma unroll
                    for (int i = 0; i < 16; ++i)
                        x[i] = xn[(size_t)t * NN + i * 64 + lane];
                }
                const float4 ta = *(const float4*)(tn + (size_t)t * NN + colbase);
                const float4 tb = *(const float4*)(tn + (size_t)t * NN + colbase + 4);
                tv[0]=0.5f*ta.x; tv[1]=0.5f*ta.y; tv[2]=0.5f*ta.z; tv[3]=0.5f*ta.w;
                tv[4]=0.5f*tb.x; tv[5]=0.5f*tb.y; tv[6]=0.5f*tb.z; tv[7]=0.5f*tb.w;
                if (stage == 0) {
#pragma unroll
                    for (int c = 0; c < 8; ++c)
#pragma unroll
                        for (int i = 0; i < 16; ++i)
                            G[i][c] = fmaxf(G[i][c], x[i] * tv[c]);
                }
            }
        }
    } else {
        // ---- out stage: y = relu(r @ Dy) for 4 consecutive steps, single Dy pass ----
        const int j4  = idx - 48;         // 0..7
        const int t0  = j4 * 4;
        const int bt0 = b * TT + t0;
        // wait for all 128 stage-2 wave flags >= t0+4 (monotone step counters)
        if (tid < 64) {
            const unsigned* base = flg + (size_t)(2 * 4 + b) * 16 * 8 * 8;
            const unsigned* g0 = base + (size_t)(tid * 2) * 8;
            const unsigned* g1 = base + (size_t)(tid * 2 + 1) * 8;
            const unsigned tgt = (unsigned)(t0 + 4);
            int g = 0;
            for (;;) {
                unsigned v0 = aldu_acq(g0), v1 = aldu_acq(g1);
                if (__all((v0 < v1 ? v0 : v1) >= tgt)) break;
                __builtin_amdgcn_s_sleep(1);
                if (++g > (1 << 22)) break;
            }
        }
        __syncthreads();
#pragma unroll
        for (int j = 0; j < 4; ++j) {
            const float* r = rb + (size_t)(bt0 + j) * NN;
            sh[tid * 4 + j]         = ald(r + tid);
            sh[(tid + 512) * 4 + j] = ald(r + tid + 512);
        }
        __syncthreads();
        const int d = tid & 255, h = tid >> 8;
        float acc[4] = {0.f, 0.f, 0.f, 0.f};
        const int n0 = h * 512;
#pragma unroll 8
        for (int n = n0; n < n0 + 512; ++n) {
            const float dv = Dy[(size_t)n * DD + d];
            const float4 rv = *(const float4*)&sh[n * 4];   // wave-uniform n -> LDS broadcast
            acc[0] += rv.x * dv; acc[1] += rv.y * dv;
            acc[2] += rv.z * dv; acc[3] += rv.w * dv;
        }
#pragma unroll
        for (int j = 0; j < 4; ++j) sh[4096 + (h * 4 + j) * 256 + d] = acc[j];
        __syncthreads();
        if (tid < 256) {
#pragma unroll
            for (int j = 0; j < 4; ++j)
                out[(size_t)(bt0 + j) * DD + tid] =
                    fmaxf(0.f, sh[4096 + j * 256 + tid] + sh[4096 + (4 + j) * 256 + tid]);
        }
    }
}

extern "C" void kernel_launch(void* const* d_in, const int* in_sizes, int n_in,
                              void* d_out, int out_size, void* d_ws, size_t ws_size,
                              hipStream_t stream) {
    const float* x_seq   = (const float*)d_in[0];
    const float* targets = (const float*)d_in[1];
    const float* E       = (const float*)d_in[2];
    const float* Dy      = (const float*)d_in[3];
    float* out = (float*)d_out;
    float* ws  = (float*)d_ws;

    // zero the per-wave flags (data is flag-protected; flags are monotone step counts)
    hipMemsetAsync(ws + FLG_OFF, 0, (size_t)FLG_WORDS * sizeof(unsigned), stream);

    precompute_kernel<<<BB * TT / 2, 256, 0, stream>>>(x_seq, targets, E, ws);
    mega_kernel<<<224, 512, 0, stream>>>(Dy, out, ws);
}

// Round 3
// 242.231 us; speedup vs baseline: 10.2615x; 10.2615x over previous
//
#include <hip/hip_runtime.h>

#define BB 4
#define TT 32
#define DD 256
#define NN 1024

// ws layout (float indices)
#define XN_OFF   0                      // xn [B*T][N]
#define TN_OFF   131072                 // tn [B*T][N]  (tn[b][t] = tgt_neurons[b][t+1])
#define PB_OFF   262144                 // p  [B*T][2][N]
#define RB_OFF   524288                 // r  [B*T][N]
#define FLG_OFF  655360                 // flags [3 stages][4 b][16 wg][32] u32 (one 128B line per flag)
#define FLG_WORDS 6144                  // 3*4*16*32
#define WS_END   (FLG_OFF + FLG_WORDS)

// ---------------- kernel 1: xn = relu(LN(x @ E)), tn shifted; grid = 64 ----------------
__global__ __launch_bounds__(256) void precompute_kernel(
    const float* __restrict__ x_seq, const float* __restrict__ targets,
    const float* __restrict__ E, float* __restrict__ ws)
{
    __shared__ float xr[4][DD];
    __shared__ float redS[4][4], redSS[4][4];
    const int blk = blockIdx.x;        // 0..63
    const int bt0 = blk * 2, bt1 = bt0 + 1;
    const int tid = threadIdx.x;
    const int lane = tid & 63, w = tid >> 6;

    xr[0][tid] = x_seq[(size_t)bt0 * DD + tid];
    xr[1][tid] = x_seq[(size_t)bt1 * DD + tid];
    xr[2][tid] = targets[(size_t)bt0 * DD + tid];
    xr[3][tid] = targets[(size_t)bt1 * DD + tid];
    __syncthreads();

    const float4* E4 = (const float4*)E;
    float4 acc[4];
#pragma unroll
    for (int r = 0; r < 4; ++r) acc[r] = make_float4(0.f, 0.f, 0.f, 0.f);
#pragma unroll 4
    for (int k = 0; k < DD; ++k) {
        float4 e = E4[(size_t)k * (NN / 4) + tid];
#pragma unroll
        for (int r = 0; r < 4; ++r) {
            float xv = xr[r][k];
            acc[r].x += xv * e.x; acc[r].y += xv * e.y;
            acc[r].z += xv * e.z; acc[r].w += xv * e.w;
        }
    }
    float s[4], ss[4];
#pragma unroll
    for (int r = 0; r < 4; ++r) {
        s[r]  = acc[r].x + acc[r].y + acc[r].z + acc[r].w;
        ss[r] = acc[r].x*acc[r].x + acc[r].y*acc[r].y + acc[r].z*acc[r].z + acc[r].w*acc[r].w;
    }
#pragma unroll
    for (int d = 1; d < 64; d <<= 1) {
#pragma unroll
        for (int r = 0; r < 4; ++r) {
            s[r]  += __shfl_xor(s[r], d, 64);
            ss[r] += __shfl_xor(ss[r], d, 64);
        }
    }
    if (lane == 0) {
#pragma unroll
        for (int r = 0; r < 4; ++r) { redS[w][r] = s[r]; redSS[w][r] = ss[r]; }
    }
    __syncthreads();
#pragma unroll
    for (int r = 0; r < 4; ++r) {
        s[r]  = redS[0][r] + redS[1][r] + redS[2][r] + redS[3][r];
        ss[r] = redSS[0][r] + redSS[1][r] + redSS[2][r] + redSS[3][r];
    }
#pragma unroll
    for (int r = 0; r < 4; ++r) {
        const float mu  = s[r] * (1.0f / NN);
        const float var = ss[r] * (1.0f / NN) - mu * mu;
        const float inv = rsqrtf(var + 1e-5f);
        float4 o;
        o.x = fmaxf(0.f, (acc[r].x - mu) * inv);
        o.y = fmaxf(0.f, (acc[r].y - mu) * inv);
        o.z = fmaxf(0.f, (acc[r].z - mu) * inv);
        o.w = fmaxf(0.f, (acc[r].w - mu) * inv);
        const int bt = (r & 1) ? bt1 : bt0;
        float* dst = nullptr;
        if (r < 2) dst = ws + XN_OFF + (size_t)bt * NN;
        else if ((bt & 31) > 0) dst = ws + TN_OFF + (size_t)(bt - 1) * NN;
        if (dst) ((float4*)dst)[tid] = o;
    }
}

// ---------------- kernel 2: 4-role persistent pipeline, acquire-free sync ----------------
// Cross-WG data always moves through RELAXED AGENT atomics (device-scope, IF$-coherent),
// so consumers never need an L2 invalidate. Polls are RELAXED + compiler fence; the only
// heavyweight op left is the producer's one RELEASE flag store per WG per step.
__device__ __forceinline__ float ald(const float* p) {
    return __hip_atomic_load(p, __ATOMIC_RELAXED, __HIP_MEMORY_SCOPE_AGENT);
}
__device__ __forceinline__ unsigned long long ald64(const unsigned long long* p) {
    return __hip_atomic_load(p, __ATOMIC_RELAXED, __HIP_MEMORY_SCOPE_AGENT);
}
__device__ __forceinline__ void ast(float* p, float v) {
    __hip_atomic_store(p, v, __ATOMIC_RELAXED, __HIP_MEMORY_SCOPE_AGENT);
}
__device__ __forceinline__ unsigned aldu_rlx(const unsigned* p) {
    return __hip_atomic_load(p, __ATOMIC_RELAXED, __HIP_MEMORY_SCOPE_AGENT);
}

__global__ __launch_bounds__(512, 2) void mega_kernel(
    const float* __restrict__ Dy, float* __restrict__ out, float* __restrict__ ws)
{
    __shared__ float sh[6144];   // stages 1-2: padded p-vector (1088); out: r[1024][4] + partial[2048]
    const int blk = blockIdx.x;  // 0..223
    const int tid = threadIdx.x;

    float* pb     = ws + PB_OFF;
    float* rb     = ws + RB_OFF;
    unsigned* flg = (unsigned*)(ws + FLG_OFF);

    if (blk < 192) {
        // ---- chain stages 0,1,2 ----
        const int stage = blk >> 6;          // 0,1,2
        const int b     = (blk >> 4) & 3;
        const int wg    = blk & 15;
        const int lane  = tid & 63;
        const int w     = tid >> 6;
        const int colbase = wg * 64 + w * 8;   // wave owns cols colbase..+7
        const int row0    = lane * 16;         // lane owns rows row0..+15
        const float* xn = ws + XN_OFF + (size_t)b * TT * NN;
        const float* tn = ws + TN_OFF + (size_t)b * TT * NN;
        unsigned* myflag = flg + ((size_t)(stage * 4 + b) * 16 + wg) * 32;
        const unsigned* inflags =
            (stage > 0) ? flg + ((size_t)((stage - 1) * 4 + b) * 16) * 32 : (const unsigned*)0;
        // wave-0 lane polls producer flag line (lane & 15); seen is a monotone cache
        unsigned seen = 0;

        float G[16][8];
#pragma unroll
        for (int i = 0; i < 16; ++i)
#pragma unroll
            for (int c = 0; c < 8; ++c)
                G[i][c] = (row0 + i == colbase + c) ? 0.01f : 0.0f;

#pragma unroll 1
        for (int t = 0; t < TT; ++t) {
            const int bt = b * TT + t;
            float* p1 = pb + (size_t)bt * 2 * NN;
            float* p2 = p1 + NN;

            float in[16], x[16];
            float v1own = 0.f;
            if (stage == 0) {
                const float4* xp = (const float4*)(xn + (size_t)t * NN + row0);
                float4 q0 = xp[0], q1 = xp[1], q2 = xp[2], q3 = xp[3];
                in[0]=q0.x; in[1]=q0.y; in[2]=q0.z; in[3]=q0.w;
                in[4]=q1.x; in[5]=q1.y; in[6]=q1.z; in[7]=q1.w;
                in[8]=q2.x; in[9]=q2.y; in[10]=q2.z; in[11]=q2.w;
                in[12]=q3.x; in[13]=q3.y; in[14]=q3.z; in[15]=q3.w;
#pragma unroll
                for (int j = 0; j < 16; ++j) x[j] = in[j];
            } else {
                // RELAXED poll by wave 0 (no acquire -> no L2 invalidate; data reads are
                // device-scope relaxed atomics that go to the IF$ coherence point anyway)
                const unsigned tgt = (unsigned)(t + 1);
                if (tid < 64) {
                    if (seen < tgt) {
                        const unsigned* p = inflags + (size_t)(tid & 15) * 32;
                        int g = 0;
                        for (;;) {
                            unsigned v = aldu_rlx(p);
                            if (v > seen) seen = v;
                            if (__all(seen >= tgt)) break;
                            __builtin_amdgcn_s_sleep(1);
                            if (++g > (1 << 22)) break;  // fail visibly, never hang
                        }
                    }
                }
                __syncthreads();
                asm volatile("" ::: "memory");   // no hoisting of data reads above the poll
                // hoist stage-2's p1 read: overlaps its latency with the exchange
                if (stage == 2) v1own = ald(p1 + colbase + (lane & 7));
                // exactly-once cooperative read -> padded LDS (one 64-bit load per thread)
                const float* src = (stage == 1) ? p1 : p2;
                union { unsigned long long u; float f[2]; } cv;
                cv.u = ald64((const unsigned long long*)src + tid);
                const int e0 = 2 * tid;
                sh[e0 + (e0 >> 4)]     = cv.f[0];
                sh[e0 + 1 + (e0 >> 4)] = cv.f[1];
                __syncthreads();
#pragma unroll
                for (int j = 0; j < 16; ++j) in[j] = sh[lane * 17 + j];
            }

            // matvec: acc[c] = partial sum for col colbase+c over this lane's rows
            float acc[8] = {0.f,0.f,0.f,0.f,0.f,0.f,0.f,0.f};
#pragma unroll
            for (int i = 0; i < 16; ++i)
#pragma unroll
                for (int c = 0; c < 8; ++c) acc[c] += in[i] * G[i][c];

            // reduce-scatter: lane ends with full sum for col colbase + (lane&7)
            float t4[8];
#pragma unroll
            for (int c = 0; c < 8; ++c) t4[c] = __shfl_xor(acc[c], 4, 64);
            const bool k2 = (lane & 4) != 0;
            float s4[4];
#pragma unroll
            for (int k = 0; k < 4; ++k) s4[k] = k2 ? (acc[4+k] + t4[4+k]) : (acc[k] + t4[k]);
            float t2[4];
#pragma unroll
            for (int k = 0; k < 4; ++k) t2[k] = __shfl_xor(s4[k], 2, 64);
            const bool k1 = (lane & 2) != 0;
            float s2[2];
#pragma unroll
            for (int k = 0; k < 2; ++k) s2[k] = k1 ? (s4[2+k] + t2[2+k]) : (s4[k] + t2[k]);
            float t1[2];
#pragma unroll
            for (int k = 0; k < 2; ++k) t1[k] = __shfl_xor(s2[k], 1, 64);
            float v = (lane & 1) ? (s2[1] + t1[1]) : (s2[0] + t1[0]);
            v += __shfl_xor(v, 8, 64);
            v += __shfl_xor(v, 16, 64);
            v += __shfl_xor(v, 32, 64);

            if (stage == 0) {
                if (lane < 8) ast(p1 + colbase + lane, v);
            } else if (stage == 1) {
                if (lane < 8) ast(p2 + colbase + lane, v);
            } else {
                const int c = colbase + (lane & 7);
                const float v2own = sh[c + (c >> 4)];   // p2 already exchanged into LDS
                float r = fmaxf(v, fmaxf(v1own, v2own));
                if (lane < 8) ast(rb + (size_t)bt * NN + colbase + lane, r);
            }
            __syncthreads();   // every wave drains its own vmcnt before the barrier
            if (tid == 0)      // single RELEASE per WG per step: publishes all the above
                __hip_atomic_store(myflag, (unsigned)(t + 1),
                                   __ATOMIC_RELEASE, __HIP_MEMORY_SCOPE_AGENT);

            // G update: G = max(G, 0.5*xn_t*tn_t^T), skip last step.
            // Plain cached loads — with acquire gone, xn/tn stay L2-warm across steps.
            if (t < TT - 1) {
                if (stage != 0) {
                    const float4* xp = (const float4*)(xn + (size_t)t * NN + row0);
                    float4 q0 = xp[0], q1 = xp[1], q2 = xp[2], q3 = xp[3];
                    x[0]=q0.x; x[1]=q0.y; x[2]=q0.z; x[3]=q0.w;
                    x[4]=q1.x; x[5]=q1.y; x[6]=q1.z; x[7]=q1.w;
                    x[8]=q2.x; x[9]=q2.y; x[10]=q2.z; x[11]=q2.w;
                    x[12]=q3.x; x[13]=q3.y; x[14]=q3.z; x[15]=q3.w;
                }
                const float4 ta = *(const float4*)(tn + (size_t)t * NN + colbase);
                const float4 tb = *(const float4*)(tn + (size_t)t * NN + colbase + 4);
                const float tv[8] = {0.5f*ta.x, 0.5f*ta.y, 0.5f*ta.z, 0.5f*ta.w,
                                     0.5f*tb.x, 0.5f*tb.y, 0.5f*tb.z, 0.5f*tb.w};
#pragma unroll
                for (int c = 0; c < 8; ++c)
#pragma unroll
                    for (int i = 0; i < 16; ++i)
                        G[i][c] = fmaxf(G[i][c], x[i] * tv[c]);
            }
        }
    } else {
        // ---- out stage: y = relu(r @ Dy) for 4 consecutive steps, single Dy pass ----
        const int k   = blk - 192;        // 0..31
        const int b   = k >> 3;
        const int t0  = (k & 7) * 4;
        const int bt0 = b * TT + t0;
        // RELAXED poll of the 16 stage-2 flags (monotone step counts)
        if (tid < 64) {
            const unsigned* p = flg + ((size_t)(2 * 4 + b) * 16 + (tid & 15)) * 32;
            const unsigned tgt = (unsigned)(t0 + 4);
            int g = 0;
            for (;;) {
                unsigned v = aldu_rlx(p);
                if (__all(v >= tgt)) break;
                __builtin_amdgcn_s_sleep(1);
                if (++g > (1 << 22)) break;
            }
        }
        __syncthreads();
        asm volatile("" ::: "memory");
#pragma unroll
        for (int j = 0; j < 4; ++j) {
            const float* r = rb + (size_t)(bt0 + j) * NN;
            sh[tid * 4 + j]         = ald(r + tid);
            sh[(tid + 512) * 4 + j] = ald(r + tid + 512);
        }
        __syncthreads();
        const int d = tid & 255, h = tid >> 8;
        float acc[4] = {0.f, 0.f, 0.f, 0.f};
        const int n0 = h * 512;
#pragma unroll 8
        for (int n = n0; n < n0 + 512; ++n) {
            const float dv = Dy[(size_t)n * DD + d];
            const float4 rv = *(const float4*)&sh[n * 4];   // wave-uniform n -> LDS broadcast
            acc[0] += rv.x * dv; acc[1] += rv.y * dv;
            acc[2] += rv.z * dv; acc[3] += rv.w * dv;
        }
#pragma unroll
        for (int j = 0; j < 4; ++j) sh[4096 + (h * 4 + j) * 256 + d] = acc[j];
        __syncthreads();
        if (tid < 256) {
#pragma unroll
            for (int j = 0; j < 4; ++j)
                out[(size_t)(bt0 + j) * DD + tid] =
                    fmaxf(0.f, sh[4096 + j * 256 + tid] + sh[4096 + (4 + j) * 256 + tid]);
        }
    }
}

extern "C" void kernel_launch(void* const* d_in, const int* in_sizes, int n_in,
                              void* d_out, int out_size, void* d_ws, size_t ws_size,
                              hipStream_t stream) {
    const float* x_seq   = (const float*)d_in[0];
    const float* targets = (const float*)d_in[1];
    const float* E       = (const float*)d_in[2];
    const float* Dy      = (const float*)d_in[3];
    float* out = (float*)d_out;
    float* ws  = (float*)d_ws;

    // zero the flags (data is flag-protected; flags are monotone step counts)
    hipMemsetAsync(ws + FLG_OFF, 0, (size_t)FLG_WORDS * sizeof(unsigned), stream);

    precompute_kernel<<<BB * TT / 2, 256, 0, stream>>>(x_seq, targets, E, ws);
    mega_kernel<<<224, 512, 0, stream>>>(Dy, out, ws);
}

// Round 4
// 213.626 us; speedup vs baseline: 11.6355x; 1.1339x over previous
//
#include <hip/hip_runtime.h>

#define BB 4
#define TT 32
#define DD 256
#define NN 1024

// ws layout (float indices)
#define XN_OFF   0                      // xn [B*T][N]
#define TN_OFF   131072                 // tn [B*T][N]  (tn[b][t] = tgt_neurons[b][t+1])
#define PB_OFF   262144                 // p  [B*T][2][N]
#define RB_OFF   524288                 // r  [B*T][N]
#define FLG_OFF  655360                 // flags [3 stages][4 b][16 wg][32] u32 (one 128B line per flag)
#define FLG_WORDS 6144                  // 3*4*16*32
#define WS_END   (FLG_OFF + FLG_WORDS)

// ---------------- kernel 1: xn = relu(LN(x @ E)), tn shifted; grid = 64 ----------------
__global__ __launch_bounds__(256) void precompute_kernel(
    const float* __restrict__ x_seq, const float* __restrict__ targets,
    const float* __restrict__ E, float* __restrict__ ws)
{
    __shared__ float xr[4][DD];
    __shared__ float redS[4][4], redSS[4][4];
    const int blk = blockIdx.x;        // 0..63
    const int bt0 = blk * 2, bt1 = bt0 + 1;
    const int tid = threadIdx.x;
    const int lane = tid & 63, w = tid >> 6;

    xr[0][tid] = x_seq[(size_t)bt0 * DD + tid];
    xr[1][tid] = x_seq[(size_t)bt1 * DD + tid];
    xr[2][tid] = targets[(size_t)bt0 * DD + tid];
    xr[3][tid] = targets[(size_t)bt1 * DD + tid];
    __syncthreads();

    const float4* E4 = (const float4*)E;
    float4 acc[4];
#pragma unroll
    for (int r = 0; r < 4; ++r) acc[r] = make_float4(0.f, 0.f, 0.f, 0.f);
#pragma unroll 4
    for (int k = 0; k < DD; ++k) {
        float4 e = E4[(size_t)k * (NN / 4) + tid];
#pragma unroll
        for (int r = 0; r < 4; ++r) {
            float xv = xr[r][k];
            acc[r].x += xv * e.x; acc[r].y += xv * e.y;
            acc[r].z += xv * e.z; acc[r].w += xv * e.w;
        }
    }
    float s[4], ss[4];
#pragma unroll
    for (int r = 0; r < 4; ++r) {
        s[r]  = acc[r].x + acc[r].y + acc[r].z + acc[r].w;
        ss[r] = acc[r].x*acc[r].x + acc[r].y*acc[r].y + acc[r].z*acc[r].z + acc[r].w*acc[r].w;
    }
#pragma unroll
    for (int d = 1; d < 64; d <<= 1) {
#pragma unroll
        for (int r = 0; r < 4; ++r) {
            s[r]  += __shfl_xor(s[r], d, 64);
            ss[r] += __shfl_xor(ss[r], d, 64);
        }
    }
    if (lane == 0) {
#pragma unroll
        for (int r = 0; r < 4; ++r) { redS[w][r] = s[r]; redSS[w][r] = ss[r]; }
    }
    __syncthreads();
#pragma unroll
    for (int r = 0; r < 4; ++r) {
        s[r]  = redS[0][r] + redS[1][r] + redS[2][r] + redS[3][r];
        ss[r] = redSS[0][r] + redSS[1][r] + redSS[2][r] + redSS[3][r];
    }
#pragma unroll
    for (int r = 0; r < 4; ++r) {
        const float mu  = s[r] * (1.0f / NN);
        const float var = ss[r] * (1.0f / NN) - mu * mu;
        const float inv = rsqrtf(var + 1e-5f);
        float4 o;
        o.x = fmaxf(0.f, (acc[r].x - mu) * inv);
        o.y = fmaxf(0.f, (acc[r].y - mu) * inv);
        o.z = fmaxf(0.f, (acc[r].z - mu) * inv);
        o.w = fmaxf(0.f, (acc[r].w - mu) * inv);
        const int bt = (r & 1) ? bt1 : bt0;
        float* dst = nullptr;
        if (r < 2) dst = ws + XN_OFF + (size_t)bt * NN;
        else if ((bt & 31) > 0) dst = ws + TN_OFF + (size_t)(bt - 1) * NN;
        if (dst) ((float4*)dst)[tid] = o;
    }
}

// ---------------- kernel 2: 4-role persistent pipeline, paired steps ----------------
// Cross-WG data moves through RELAXED AGENT atomics (device-scope, IF$-coherent);
// polls are RELAXED + compiler fence; one RELEASE flag store per WG per PAIR of steps.
// Pairing halves the per-step count of serial device-scope latency segments
// (poll, gather, store-drain, release), which R0-R3 showed is the actual cost.
__device__ __forceinline__ float ald(const float* p) {
    return __hip_atomic_load(p, __ATOMIC_RELAXED, __HIP_MEMORY_SCOPE_AGENT);
}
__device__ __forceinline__ unsigned long long ald64(const unsigned long long* p) {
    return __hip_atomic_load(p, __ATOMIC_RELAXED, __HIP_MEMORY_SCOPE_AGENT);
}
__device__ __forceinline__ void ast(float* p, float v) {
    __hip_atomic_store(p, v, __ATOMIC_RELAXED, __HIP_MEMORY_SCOPE_AGENT);
}
__device__ __forceinline__ unsigned aldu_rlx(const unsigned* p) {
    return __hip_atomic_load(p, __ATOMIC_RELAXED, __HIP_MEMORY_SCOPE_AGENT);
}

__global__ __launch_bounds__(512, 1) void mega_kernel(
    const float* __restrict__ Dy, float* __restrict__ out, float* __restrict__ ws)
{
    __shared__ float sh[6144];   // chain: two padded p-vectors (1088 each, base 0 / 1152); out: r[1024][4]+partial
    const int blk = blockIdx.x;  // 0..223  (grid <= 256 CUs -> 1 WG/CU, so (512,1) costs no occupancy)
    const int tid = threadIdx.x;

    float* pb     = ws + PB_OFF;
    float* rb     = ws + RB_OFF;
    unsigned* flg = (unsigned*)(ws + FLG_OFF);

    if (blk < 192) {
        // ---- chain stages 0,1,2 ----
        const int stage = blk >> 6;          // 0,1,2
        const int b     = (blk >> 4) & 3;
        const int wg    = blk & 15;
        const int lane  = tid & 63;
        const int w     = tid >> 6;
        const int colbase = wg * 64 + w * 8;   // wave owns cols colbase..+7
        const int row0    = lane * 16;         // lane owns rows row0..+15
        const float* xn = ws + XN_OFF + (size_t)b * TT * NN;
        const float* tn = ws + TN_OFF + (size_t)b * TT * NN;
        unsigned* myflag = flg + ((size_t)(stage * 4 + b) * 16 + wg) * 32;
        const unsigned* inflags =
            (stage > 0) ? flg + ((size_t)((stage - 1) * 4 + b) * 16) * 32 : (const unsigned*)0;
        unsigned seen = 0;   // monotone cache of min producer flag seen by this lane

        float G[16][8];
#pragma unroll
        for (int i = 0; i < 16; ++i)
#pragma unroll
            for (int c = 0; c < 8; ++c)
                G[i][c] = (row0 + i == colbase + c) ? 0.01f : 0.0f;

#pragma unroll 1
        for (int t = 0; t < TT; t += 2) {
            const int bt = b * TT + t;
            float* p1t = pb + (size_t)bt * 2 * NN;
            float* p2t = p1t + NN;
            float* p1u = p2t + NN;      // step t+1 buffers
            float* p2u = p1u + NN;

            float in_t[16], in_u[16];
            float v1own_t = 0.f, v1own_u = 0.f;

            if (stage == 0) {
                const float4* xp = (const float4*)(xn + (size_t)t * NN + row0);
                const float4* xq = (const float4*)(xn + (size_t)(t + 1) * NN + row0);
                float4 q0 = xp[0], q1 = xp[1], q2 = xp[2], q3 = xp[3];
                float4 r0 = xq[0], r1 = xq[1], r2 = xq[2], r3 = xq[3];
                in_t[0]=q0.x; in_t[1]=q0.y; in_t[2]=q0.z; in_t[3]=q0.w;
                in_t[4]=q1.x; in_t[5]=q1.y; in_t[6]=q1.z; in_t[7]=q1.w;
                in_t[8]=q2.x; in_t[9]=q2.y; in_t[10]=q2.z; in_t[11]=q2.w;
                in_t[12]=q3.x; in_t[13]=q3.y; in_t[14]=q3.z; in_t[15]=q3.w;
                in_u[0]=r0.x; in_u[1]=r0.y; in_u[2]=r0.z; in_u[3]=r0.w;
                in_u[4]=r1.x; in_u[5]=r1.y; in_u[6]=r1.z; in_u[7]=r1.w;
                in_u[8]=r2.x; in_u[9]=r2.y; in_u[10]=r2.z; in_u[11]=r2.w;
                in_u[12]=r3.x; in_u[13]=r3.y; in_u[14]=r3.z; in_u[15]=r3.w;
            } else {
                // one RELAXED poll covers both steps: all producers at flag >= t+2
                const unsigned tgt = (unsigned)(t + 2);
                if (tid < 64) {
                    if (seen < tgt) {
                        const unsigned* p = inflags + (size_t)(tid & 15) * 32;
                        int g = 0;
                        for (;;) {
                            unsigned v = aldu_rlx(p);
                            if (v > seen) seen = v;
                            if (__all(seen >= tgt)) break;
                            __builtin_amdgcn_s_sleep(1);
                            if (++g > (1 << 22)) break;  // fail visibly, never hang
                        }
                    }
                }
                __syncthreads();
                asm volatile("" ::: "memory");   // no hoisting of data reads above the poll
                // stage-2 p1 reads for both steps: in flight together with the gathers
                if (stage == 2) {
                    v1own_t = ald(p1t + colbase + (lane & 7));
                    v1own_u = ald(p1u + colbase + (lane & 7));
                }
                // cooperative exchange of BOTH vectors (independent loads, overlapped latency)
                const float* st = (stage == 1) ? p1t : p2t;
                const float* su = (stage == 1) ? p1u : p2u;
                union { unsigned long long u; float f[2]; } ct, cu;
                ct.u = ald64((const unsigned long long*)st + tid);
                cu.u = ald64((const unsigned long long*)su + tid);
                const int e0 = 2 * tid;
                sh[e0 + (e0 >> 4)]            = ct.f[0];
                sh[e0 + 1 + (e0 >> 4)]        = ct.f[1];
                sh[1152 + e0 + (e0 >> 4)]     = cu.f[0];
                sh[1152 + e0 + 1 + (e0 >> 4)] = cu.f[1];
                __syncthreads();
#pragma unroll
                for (int j = 0; j < 16; ++j) {
                    in_t[j] = sh[lane * 17 + j];
                    in_u[j] = sh[1152 + lane * 17 + j];
                }
            }

            // ================= step t =================
            {
                float acc[8] = {0.f,0.f,0.f,0.f,0.f,0.f,0.f,0.f};
#pragma unroll
                for (int i = 0; i < 16; ++i)
#pragma unroll
                    for (int c = 0; c < 8; ++c) acc[c] += in_t[i] * G[i][c];
                float t4[8];
#pragma unroll
                for (int c = 0; c < 8; ++c) t4[c] = __shfl_xor(acc[c], 4, 64);
                const bool k2 = (lane & 4) != 0;
                float s4[4];
#pragma unroll
                for (int k = 0; k < 4; ++k) s4[k] = k2 ? (acc[4+k] + t4[4+k]) : (acc[k] + t4[k]);
                float t2[4];
#pragma unroll
                for (int k = 0; k < 4; ++k) t2[k] = __shfl_xor(s4[k], 2, 64);
                const bool k1 = (lane & 2) != 0;
                float s2[2];
#pragma unroll
                for (int k = 0; k < 2; ++k) s2[k] = k1 ? (s4[2+k] + t2[2+k]) : (s4[k] + t2[k]);
                float t1[2];
#pragma unroll
                for (int k = 0; k < 2; ++k) t1[k] = __shfl_xor(s2[k], 1, 64);
                float v = (lane & 1) ? (s2[1] + t1[1]) : (s2[0] + t1[0]);
                v += __shfl_xor(v, 8, 64);
                v += __shfl_xor(v, 16, 64);
                v += __shfl_xor(v, 32, 64);

                if (stage == 0) {
                    if (lane < 8) ast(p1t + colbase + lane, v);
                } else if (stage == 1) {
                    if (lane < 8) ast(p2t + colbase + lane, v);
                } else {
                    const int c = colbase + (lane & 7);
                    const float v2own = sh[c + (c >> 4)];
                    float r = fmaxf(v, fmaxf(v1own_t, v2own));
                    if (lane < 8) ast(rb + (size_t)bt * NN + colbase + lane, r);
                }
            }

            // G update for step t (t even <= 30, always < TT-1)
            {
                float x[16];
                if (stage == 0) {
#pragma unroll
                    for (int j = 0; j < 16; ++j) x[j] = in_t[j];
                } else {
                    const float4* xp = (const float4*)(xn + (size_t)t * NN + row0);
                    float4 q0 = xp[0], q1 = xp[1], q2 = xp[2], q3 = xp[3];
                    x[0]=q0.x; x[1]=q0.y; x[2]=q0.z; x[3]=q0.w;
                    x[4]=q1.x; x[5]=q1.y; x[6]=q1.z; x[7]=q1.w;
                    x[8]=q2.x; x[9]=q2.y; x[10]=q2.z; x[11]=q2.w;
                    x[12]=q3.x; x[13]=q3.y; x[14]=q3.z; x[15]=q3.w;
                }
                const float4 ta = *(const float4*)(tn + (size_t)t * NN + colbase);
                const float4 tb = *(const float4*)(tn + (size_t)t * NN + colbase + 4);
                const float tv[8] = {0.5f*ta.x, 0.5f*ta.y, 0.5f*ta.z, 0.5f*ta.w,
                                     0.5f*tb.x, 0.5f*tb.y, 0.5f*tb.z, 0.5f*tb.w};
#pragma unroll
                for (int c = 0; c < 8; ++c)
#pragma unroll
                    for (int i = 0; i < 16; ++i)
                        G[i][c] = fmaxf(G[i][c], x[i] * tv[c]);
            }

            // ================= step t+1 =================
            {
                float acc[8] = {0.f,0.f,0.f,0.f,0.f,0.f,0.f,0.f};
#pragma unroll
                for (int i = 0; i < 16; ++i)
#pragma unroll
                    for (int c = 0; c < 8; ++c) acc[c] += in_u[i] * G[i][c];
                float t4[8];
#pragma unroll
                for (int c = 0; c < 8; ++c) t4[c] = __shfl_xor(acc[c], 4, 64);
                const bool k2 = (lane & 4) != 0;
                float s4[4];
#pragma unroll
                for (int k = 0; k < 4; ++k) s4[k] = k2 ? (acc[4+k] + t4[4+k]) : (acc[k] + t4[k]);
                float t2[4];
#pragma unroll
                for (int k = 0; k < 4; ++k) t2[k] = __shfl_xor(s4[k], 2, 64);
                const bool k1 = (lane & 2) != 0;
                float s2[2];
#pragma unroll
                for (int k = 0; k < 2; ++k) s2[k] = k1 ? (s4[2+k] + t2[2+k]) : (s4[k] + t2[k]);
                float t1[2];
#pragma unroll
                for (int k = 0; k < 2; ++k) t1[k] = __shfl_xor(s2[k], 1, 64);
                float v = (lane & 1) ? (s2[1] + t1[1]) : (s2[0] + t1[0]);
                v += __shfl_xor(v, 8, 64);
                v += __shfl_xor(v, 16, 64);
                v += __shfl_xor(v, 32, 64);

                if (stage == 0) {
                    if (lane < 8) ast(p1u + colbase + lane, v);
                } else if (stage == 1) {
                    if (lane < 8) ast(p2u + colbase + lane, v);
                } else {
                    const int c = colbase + (lane & 7);
                    const float v2own = sh[1152 + c + (c >> 4)];
                    float r = fmaxf(v, fmaxf(v1own_u, v2own));
                    if (lane < 8) ast(rb + (size_t)(bt + 1) * NN + colbase + lane, r);
                }
            }

            __syncthreads();   // one drain for both steps' device-scope stores
            if (tid == 0)      // one RELEASE per pair: publishes steps t and t+1
                __hip_atomic_store(myflag, (unsigned)(t + 2),
                                   __ATOMIC_RELEASE, __HIP_MEMORY_SCOPE_AGENT);

            // deferred G update for step t+1 — after the release, overlaps flag propagation
            if (t + 1 < TT - 1) {
                float x[16];
                if (stage == 0) {
#pragma unroll
                    for (int j = 0; j < 16; ++j) x[j] = in_u[j];
                } else {
                    const float4* xp = (const float4*)(xn + (size_t)(t + 1) * NN + row0);
                    float4 q0 = xp[0], q1 = xp[1], q2 = xp[2], q3 = xp[3];
                    x[0]=q0.x; x[1]=q0.y; x[2]=q0.z; x[3]=q0.w;
                    x[4]=q1.x; x[5]=q1.y; x[6]=q1.z; x[7]=q1.w;
                    x[8]=q2.x; x[9]=q2.y; x[10]=q2.z; x[11]=q2.w;
                    x[12]=q3.x; x[13]=q3.y; x[14]=q3.z; x[15]=q3.w;
                }
                const float4 ta = *(const float4*)(tn + (size_t)(t + 1) * NN + colbase);
                const float4 tb = *(const float4*)(tn + (size_t)(t + 1) * NN + colbase + 4);
                const float tv[8] = {0.5f*ta.x, 0.5f*ta.y, 0.5f*ta.z, 0.5f*ta.w,
                                     0.5f*tb.x, 0.5f*tb.y, 0.5f*tb.z, 0.5f*tb.w};
#pragma unroll
                for (int c = 0; c < 8; ++c)
#pragma unroll
                    for (int i = 0; i < 16; ++i)
                        G[i][c] = fmaxf(G[i][c], x[i] * tv[c]);
            }
        }
    } else {
        // ---- out stage: y = relu(r @ Dy) for 4 consecutive steps, single Dy pass ----
        const int k   = blk - 192;        // 0..31
        const int b   = k >> 3;
        const int t0  = (k & 7) * 4;
        const int bt0 = b * TT + t0;
        // RELAXED poll of the 16 stage-2 flags (monotone pair counts; t0+4 is even)
        if (tid < 64) {
            const unsigned* p = flg + ((size_t)(2 * 4 + b) * 16 + (tid & 15)) * 32;
            const unsigned tgt = (unsigned)(t0 + 4);
            int g = 0;
            for (;;) {
                unsigned v = aldu_rlx(p);
                if (__all(v >= tgt)) break;
                __builtin_amdgcn_s_sleep(1);
                if (++g > (1 << 22)) break;
            }
        }
        __syncthreads();
        asm volatile("" ::: "memory");
#pragma unroll
        for (int j = 0; j < 4; ++j) {
            const float* r = rb + (size_t)(bt0 + j) * NN;
            sh[tid * 4 + j]         = ald(r + tid);
            sh[(tid + 512) * 4 + j] = ald(r + tid + 512);
        }
        __syncthreads();
        const int d = tid & 255, h = tid >> 8;
        float acc[4] = {0.f, 0.f, 0.f, 0.f};
        const int n0 = h * 512;
#pragma unroll 8
        for (int n = n0; n < n0 + 512; ++n) {
            const float dv = Dy[(size_t)n * DD + d];
            const float4 rv = *(const float4*)&sh[n * 4];   // wave-uniform n -> LDS broadcast
            acc[0] += rv.x * dv; acc[1] += rv.y * dv;
            acc[2] += rv.z * dv; acc[3] += rv.w * dv;
        }
#pragma unroll
        for (int j = 0; j < 4; ++j) sh[4096 + (h * 4 + j) * 256 + d] = acc[j];
        __syncthreads();
        if (tid < 256) {
#pragma unroll
            for (int j = 0; j < 4; ++j)
                out[(size_t)(bt0 + j) * DD + tid] =
                    fmaxf(0.f, sh[4096 + j * 256 + tid] + sh[4096 + (4 + j) * 256 + tid]);
        }
    }
}

extern "C" void kernel_launch(void* const* d_in, const int* in_sizes, int n_in,
                              void* d_out, int out_size, void* d_ws, size_t ws_size,
                              hipStream_t stream) {
    const float* x_seq   = (const float*)d_in[0];
    const float* targets = (const float*)d_in[1];
    const float* E       = (const float*)d_in[2];
    const float* Dy      = (const float*)d_in[3];
    float* out = (float*)d_out;
    float* ws  = (float*)d_ws;

    // zero the flags (data is flag-protected; flags are monotone step counts)
    hipMemsetAsync(ws + FLG_OFF, 0, (size_t)FLG_WORDS * sizeof(unsigned), stream);

    precompute_kernel<<<BB * TT / 2, 256, 0, stream>>>(x_seq, targets, E, ws);
    mega_kernel<<<224, 512, 0, stream>>>(Dy, out, ws);
}